// Round 1
// 94.345 us; speedup vs baseline: 1.0045x; 1.0045x over previous
//
#include <hip/hip_runtime.h>

// x[C=64][H=512][W=512] fp32 -> out[C=64][OH=256][OW=256] fp32.
// 2x2 stride-2 window, MaxNetwork math:
//   pairmax(a,b) = relu(relu(a-b) + relu(b)) = max(a-b,0) + max(b,0)
// Window order (0,0),(0,1),(1,0),(1,1):
//   m1 = pairmax(w00,w01); m2 = pairmax(w10,w11); out = pairmax(m1,m2).
//
// R1: 4 outputs/thread (two column-pairs 128 output-cols apart), 4 independent
// dwordx4 loads in flight per thread. Every load instruction is 64 lanes x 16B
// contiguous (1KB/wave); every store instruction is 64 lanes x 8B contiguous
// (512B/wave). Total HBM traffic unchanged (83.9 MB, the mandatory minimum).

#define C_  64
#define H_  512
#define W_  512
#define OH_ 256
#define OW_ 256

__device__ __forceinline__ float pairmax(float a, float b) {
    return fmaxf(a - b, 0.0f) + fmaxf(b, 0.0f);
}

__global__ __launch_bounds__(256) void maxnet_pool_kernel(
        const float* __restrict__ x, float* __restrict__ out) {
    const int tid  = blockIdx.x * blockDim.x + threadIdx.x; // [0, C*OH*OW/4)
    const int ow2  = tid & 63;      // column-pair index in left half (out cols 0..127)
    const int rest = tid >> 6;      // c*OH + oh, [0, 16384)

    // Input row pair for this output row: rows 2*oh, 2*oh+1 of channel c
    // == flat rows 2*rest, 2*rest+1.
    const int ibase = (rest << 1) * W_ + (ow2 << 2);  // 16B-aligned

    // Left-half window pair (out cols 2*ow2, 2*ow2+1)
    const float4 a0 = *reinterpret_cast<const float4*>(x + ibase);        // row 2*oh
    const float4 a1 = *reinterpret_cast<const float4*>(x + ibase + W_);   // row 2*oh+1
    // Right-half window pair (out cols 2*ow2+128, 2*ow2+129) -> input cols +256
    const float4 b0 = *reinterpret_cast<const float4*>(x + ibase + 256);
    const float4 b1 = *reinterpret_cast<const float4*>(x + ibase + 256 + W_);

    float2 oa, ob;
    oa.x = pairmax(pairmax(a0.x, a0.y), pairmax(a1.x, a1.y));
    oa.y = pairmax(pairmax(a0.z, a0.w), pairmax(a1.z, a1.w));
    ob.x = pairmax(pairmax(b0.x, b0.y), pairmax(b1.x, b1.y));
    ob.y = pairmax(pairmax(b0.z, b0.w), pairmax(b1.z, b1.w));

    const int obase = rest * OW_ + (ow2 << 1);
    *reinterpret_cast<float2*>(out + obase)       = oa;
    *reinterpret_cast<float2*>(out + obase + 128) = ob;
}

extern "C" void kernel_launch(void* const* d_in, const int* in_sizes, int n_in,
                              void* d_out, int out_size, void* d_ws, size_t ws_size,
                              hipStream_t stream) {
    const float* x = (const float*)d_in[0];
    float* out = (float*)d_out;
    const int n_threads = C_ * OH_ * (OW_ / 4);  // 1,048,576
    const int block = 256;
    const int grid = n_threads / block;          // 4096
    maxnet_pool_kernel<<<grid, block, 0, stream>>>(x, out);
}